// Round 1
// baseline (35.231 us; speedup 1.0000x reference)
//
#include <hip/hip_runtime.h>

#define NWALKERS 4096
#define NIN 24        // NPART * NDIM
#define HID 256

__global__ __launch_bounds__(256) void kinetic_kernel(
    const float* __restrict__ x,   // [NWALKERS, NIN]
    const float* __restrict__ W1,  // [NIN, HID] row-major
    const float* __restrict__ b1,  // [HID]
    const float* __restrict__ W2,  // [HID] (shape (HID,1) flattened)
    float* __restrict__ out)       // [NWALKERS]
{
    const int w = blockIdx.x;      // walker
    const int j = threadIdx.x;     // hidden unit

    __shared__ float zs[NIN];
    __shared__ float wave_g[4][NIN];
    __shared__ float wave_l[4];

    if (j < NIN) zs[j] = x[w * NIN + j];
    __syncthreads();

    // Load column j of W1 (coalesced across threads), compute pre-activation
    // a_j and column sum-of-squares in one pass; keep column in registers.
    float wreg[NIN];
    float a = b1[j];
    float csum = 0.f;
    #pragma unroll
    for (int i = 0; i < NIN; ++i) {
        float wv = W1[i * HID + j];
        wreg[i] = wv;
        a = fmaf(zs[i], wv, a);
        csum = fmaf(wv, wv, csum);
    }

    float t = tanhf(a);
    float s = 1.f - t * t;
    float w2 = W2[j];
    float u = w2 * s;                        // gradient coefficient
    float lapp = -2.f * w2 * t * s * csum;   // laplacian contribution of unit j

    // Per-lane partial gradient vector p_i = u * W1[i,j]
    float p[NIN];
    #pragma unroll
    for (int i = 0; i < NIN; ++i) p[i] = u * wreg[i];

    // 64-lane butterfly reduction (wave = 64 on CDNA)
    #pragma unroll
    for (int d = 1; d < 64; d <<= 1) {
        #pragma unroll
        for (int i = 0; i < NIN; ++i) p[i] += __shfl_xor(p[i], d, 64);
        lapp += __shfl_xor(lapp, d, 64);
    }

    const int wave = j >> 6;
    const int lane = j & 63;
    if (lane == 0) {
        #pragma unroll
        for (int i = 0; i < NIN; ++i) wave_g[wave][i] = p[i];
        wave_l[wave] = lapp;
    }
    __syncthreads();

    if (j == 0) {
        float lap = wave_l[0] + wave_l[1] + wave_l[2] + wave_l[3];
        float gg = 0.f;
        #pragma unroll
        for (int i = 0; i < NIN; ++i) {
            float g = wave_g[0][i] + wave_g[1][i] + wave_g[2][i] + wave_g[3][i];
            gg = fmaf(g, g, gg);
        }
        out[w] = -0.5f * (lap + gg);
    }
}

extern "C" void kernel_launch(void* const* d_in, const int* in_sizes, int n_in,
                              void* d_out, int out_size, void* d_ws, size_t ws_size,
                              hipStream_t stream) {
    const float* x  = (const float*)d_in[0];  // [4096, 8, 3]
    const float* W1 = (const float*)d_in[1];  // [24, 256]
    const float* b1 = (const float*)d_in[2];  // [256]
    const float* W2 = (const float*)d_in[3];  // [256, 1]
    // d_in[4] = b2, unused (constant offset drops out of all derivatives)
    float* out = (float*)d_out;               // [4096]

    kinetic_kernel<<<NWALKERS, HID, 0, stream>>>(x, W1, b1, W2, out);
}

// Round 2
// 13.911 us; speedup vs baseline: 2.5325x; 2.5325x over previous
//
#include <hip/hip_runtime.h>

#define NWALKERS 4096
#define NIN 24        // NPART * NDIM
#define HID 256
#define WPB 2         // walkers per block
#define CHUNKS 8
#define CW 32         // chunk width (CHUNKS*CW == HID)
#define CPAD 36       // padded chunk stride (16B-aligned, bank-conflict-free)

__global__ __launch_bounds__(256) void kinetic_kernel(
    const float* __restrict__ x,   // [NWALKERS, NIN]
    const float* __restrict__ W1,  // [NIN, HID]
    const float* __restrict__ b1,  // [HID]
    const float* __restrict__ W2,  // [HID]
    float* __restrict__ out)       // [NWALKERS]
{
    const int w0 = blockIdx.x * WPB;
    const int j  = threadIdx.x;

    __shared__ __align__(16) float zs[WPB][NIN];
    __shared__ __align__(16) float us[WPB][CHUNKS * CPAD];
    __shared__ float wl[WPB][4];
    __shared__ float gsq[WPB][NIN];

    // Load WPB*24 = 48 floats of x as 12 float4s (coalesced)
    if (j < WPB * NIN / 4) {
        ((float4*)&zs[0][0])[j] = ((const float4*)(x + w0 * NIN))[j];
    }
    __syncthreads();

    // Phase 1: thread j = hidden unit j. One pass over W1 column j
    // (coalesced dword loads) feeds both walkers' pre-activations and
    // the walker-independent column sum-of-squares.
    float a0 = b1[j];
    float a1 = a0;
    float csum = 0.f;
    #pragma unroll
    for (int i = 0; i < NIN; ++i) {
        float wv = W1[i * HID + j];
        a0 = fmaf(zs[0][i], wv, a0);
        a1 = fmaf(zs[1][i], wv, a1);
        csum = fmaf(wv, wv, csum);
    }
    const float w2 = W2[j];

    // Fast tanh: t = 1 - 2/(exp(2a)+1)  (NaN-safe at +/-inf)
    float u0, u1, lap0, lap1;
    {
        float e = __expf(2.f * a0);
        float t = 1.f - 2.f * __builtin_amdgcn_rcpf(e + 1.f);
        float s = 1.f - t * t;
        u0 = w2 * s;
        lap0 = -2.f * w2 * t * s * csum;
    }
    {
        float e = __expf(2.f * a1);
        float t = 1.f - 2.f * __builtin_amdgcn_rcpf(e + 1.f);
        float s = 1.f - t * t;
        u1 = w2 * s;
        lap1 = -2.f * w2 * t * s * csum;
    }

    // Stash u_j in padded LDS chunks (chunk c = j/32, stride 36 floats:
    // 16B-aligned and conflict-free for float4 reads across c).
    {
        int c = j >> 5, jj = j & 31;
        us[0][c * CPAD + jj] = u0;
        us[1][c * CPAD + jj] = u1;
    }

    // lap is a plain scalar sum: 6-step wave butterfly (12 shfl total)
    #pragma unroll
    for (int d = 1; d < 64; d <<= 1) {
        lap0 += __shfl_xor(lap0, d, 64);
        lap1 += __shfl_xor(lap1, d, 64);
    }
    if ((j & 63) == 0) {
        wl[0][j >> 6] = lap0;
        wl[1][j >> 6] = lap1;
    }
    __syncthreads();

    // Phase 2: gradient g_i = sum_j u_j * W1[i,j] as (i, chunk) partials.
    // 192 threads: i = j>>3 in [0,24), c = j&7 in [0,8). Each does 32
    // vectorized FMAs per walker, then 3-step shfl over the 8 chunk lanes.
    if (j < NIN * CHUNKS) {
        const int c = j & 7, i = j >> 3;
        const float4* wrow = (const float4*)(W1 + i * HID + c * CW);
        const float4* up0  = (const float4*)&us[0][c * CPAD];
        const float4* up1  = (const float4*)&us[1][c * CPAD];
        float g0 = 0.f, g1 = 0.f;
        #pragma unroll
        for (int k = 0; k < CW / 4; ++k) {
            float4 wv = wrow[k];
            float4 q0 = up0[k];
            float4 q1 = up1[k];
            g0 = fmaf(wv.x, q0.x, g0); g0 = fmaf(wv.y, q0.y, g0);
            g0 = fmaf(wv.z, q0.z, g0); g0 = fmaf(wv.w, q0.w, g0);
            g1 = fmaf(wv.x, q1.x, g1); g1 = fmaf(wv.y, q1.y, g1);
            g1 = fmaf(wv.z, q1.z, g1); g1 = fmaf(wv.w, q1.w, g1);
        }
        #pragma unroll
        for (int d = 1; d < 8; d <<= 1) {
            g0 += __shfl_xor(g0, d, 64);
            g1 += __shfl_xor(g1, d, 64);
        }
        if (c == 0) {
            gsq[0][i] = g0 * g0;
            gsq[1][i] = g1 * g1;
        }
    }
    __syncthreads();

    if (j < WPB) {
        float lap = wl[j][0] + wl[j][1] + wl[j][2] + wl[j][3];
        float gg = 0.f;
        #pragma unroll
        for (int i = 0; i < NIN; ++i) gg += gsq[j][i];
        out[w0 + j] = -0.5f * (lap + gg);
    }
}

extern "C" void kernel_launch(void* const* d_in, const int* in_sizes, int n_in,
                              void* d_out, int out_size, void* d_ws, size_t ws_size,
                              hipStream_t stream) {
    const float* x  = (const float*)d_in[0];  // [4096, 8, 3]
    const float* W1 = (const float*)d_in[1];  // [24, 256]
    const float* b1 = (const float*)d_in[2];  // [256]
    const float* W2 = (const float*)d_in[3];  // [256, 1]
    // d_in[4] = b2 unused (constant offset drops out of derivatives)
    float* out = (float*)d_out;               // [4096]

    kinetic_kernel<<<NWALKERS / WPB, HID, 0, stream>>>(x, W1, b1, W2, out);
}

// Round 3
// 10.762 us; speedup vs baseline: 3.2736x; 1.2926x over previous
//
#include <hip/hip_runtime.h>

#define NWALKERS 4096
#define NIN 24        // NPART * NDIM
#define HID 256
#define WPB 4         // walkers per block

__device__ __forceinline__ float rdlane(float v, int l) {
    return __uint_as_float(__builtin_amdgcn_readlane(__float_as_uint(v), l));
}

__global__ __launch_bounds__(256) void kinetic_kernel(
    const float* __restrict__ x,   // [NWALKERS, NIN]
    const float* __restrict__ W1,  // [NIN, HID]
    const float* __restrict__ b1,  // [HID]
    const float* __restrict__ W2,  // [HID]
    float* __restrict__ out)       // [NWALKERS]
{
    const int tid  = threadIdx.x;
    const int w0   = blockIdx.x * WPB;
    const int lane = tid & 63;

    // us[w][c][.] : u_j chunks, base bank (264w+132c)%32 = 8w+4c -> all 8
    //               (w,c) groups hit distinct 4-bank groups: conflict-free b128.
    __shared__ __align__(16) float us[WPB][2][132];
    __shared__ float ls[HID * 5 + 8];   // lapp_j at ls[j*5+w], stride 5 kills bank aliasing
    __shared__ float gs[WPB][25];
    __shared__ float lp[WPB][8];

    // ---- Phase 1: thread = hidden unit j = tid, 4 walkers at once ----
    // Block-uniform z (96 floats) lives in 2 VGPRs/lane; broadcast by
    // v_readlane (SALU pipe, dual-issues with VALU FMA stream). No LDS, no barrier.
    const float xr0 = x[w0 * NIN + lane];              // elements 0..63
    const float xr1 = x[w0 * NIN + 64 + (lane & 31)];  // elements 64..95

    float a0 = b1[tid];
    float a1 = a0, a2 = a0, a3 = a0;
    float csum = 0.f;
    #pragma unroll
    for (int i = 0; i < NIN; ++i) {
        const float wv = W1[i * HID + tid];
        const int i0 = 0 * NIN + i;   // 0..23   -> xr0
        const int i1 = 1 * NIN + i;   // 24..47  -> xr0
        const int i2 = 2 * NIN + i;   // 48..71  -> xr0/xr1
        const int i3 = 3 * NIN + i;   // 72..95  -> xr1
        const float z0 = rdlane(xr0, i0);
        const float z1 = rdlane(xr0, i1);
        const float z2 = (i2 < 64) ? rdlane(xr0, i2) : rdlane(xr1, i2 - 64);
        const float z3 = rdlane(xr1, i3 - 64);
        a0 = fmaf(z0, wv, a0);
        a1 = fmaf(z1, wv, a1);
        a2 = fmaf(z2, wv, a2);
        a3 = fmaf(z3, wv, a3);
        csum = fmaf(wv, wv, csum);
    }
    const float w2 = W2[tid];
    const int hi = tid >> 7, lo = tid & 127;

    #pragma unroll
    for (int w = 0; w < WPB; ++w) {
        const float a = (w == 0) ? a0 : (w == 1) ? a1 : (w == 2) ? a2 : a3;
        // fast tanh: t = 1 - 2/(exp(2a)+1)
        const float e = __expf(2.f * a);
        const float t = 1.f - 2.f * __builtin_amdgcn_rcpf(e + 1.f);
        const float s = 1.f - t * t;
        us[w][hi][lo]    = w2 * s;                  // gradient coefficient u_j
        ls[tid * 5 + w]  = -2.f * w2 * t * s * csum; // laplacian term lapp_j
    }
    __syncthreads();

    // ---- Phase 2 ----
    if (tid < 192) {
        // gradient g_i: (w = tid&3, c = (tid>>2)&1, i = tid>>3), 128-elem dot
        const int w = tid & 3, c = (tid >> 2) & 1, r = tid >> 3;
        const float4* gp = (const float4*)(W1 + r * HID + c * 128);
        const float4* up = (const float4*)&us[w][c][0];
        float g = 0.f;
        #pragma unroll 4
        for (int k = 0; k < 32; ++k) {
            const float4 wv = gp[k];
            const float4 uv = up[k];
            g = fmaf(wv.x, uv.x, g);
            g = fmaf(wv.y, uv.y, g);
            g = fmaf(wv.z, uv.z, g);
            g = fmaf(wv.w, uv.w, g);
        }
        g += __shfl_xor(g, 4, 64);    // combine the two 128-chunks (bit2 = c)
        if (c == 0) gs[w][r] = g * g;
    } else if (tid < 224) {
        // laplacian: 32 lanes of wave 3 comb-reduce ls (conflict-free pattern)
        const int p = tid - 192, w = p >> 3, k = p & 7;
        float sacc = 0.f;
        #pragma unroll
        for (int t = 0; t < 32; ++t) sacc += ls[(8 * t + k) * 5 + w];
        lp[w][k] = sacc;
    }
    __syncthreads();

    if (tid < WPB) {
        float gg = 0.f;
        #pragma unroll
        for (int r = 0; r < 24; ++r) gg += gs[tid][r];
        float lap = 0.f;
        #pragma unroll
        for (int k = 0; k < 8; ++k) lap += lp[tid][k];
        out[w0 + tid] = -0.5f * (lap + gg);
    }
}

extern "C" void kernel_launch(void* const* d_in, const int* in_sizes, int n_in,
                              void* d_out, int out_size, void* d_ws, size_t ws_size,
                              hipStream_t stream) {
    const float* x  = (const float*)d_in[0];  // [4096, 8, 3]
    const float* W1 = (const float*)d_in[1];  // [24, 256]
    const float* b1 = (const float*)d_in[2];  // [256]
    const float* W2 = (const float*)d_in[3];  // [256, 1]
    // d_in[4] = b2 unused (constant offset drops out of derivatives)
    float* out = (float*)d_out;               // [4096]

    kinetic_kernel<<<NWALKERS / WPB, HID, 0, stream>>>(x, W1, b1, W2, out);
}

// Round 4
// 10.571 us; speedup vs baseline: 3.3327x; 1.0181x over previous
//
#include <hip/hip_runtime.h>

#define NWALKERS 4096
#define NIN 24        // NPART * NDIM
#define HID 256
#define WPB 4         // walkers per block

__global__ __launch_bounds__(256) void kinetic_kernel(
    const float* __restrict__ x,   // [NWALKERS, NIN]
    const float* __restrict__ W1,  // [NIN, HID]
    const float* __restrict__ b1,  // [HID]
    const float* __restrict__ W2,  // [HID]
    float* __restrict__ out)       // [NWALKERS]
{
    const int tid = threadIdx.x;
    const int w0  = blockIdx.x * WPB;

    // us[w][c][.] : u_j chunks, base bank (264w+132c)%32 = 8w+4c -> 8 distinct
    //               4-bank groups: conflict-free float4 reads.
    __shared__ __align__(16) float us[WPB][2][132];
    __shared__ float ls[HID * 5 + 8];   // lapp_j at ls[j*5+w], stride 5 kills aliasing
    __shared__ float gs[WPB][25];
    __shared__ float lp[WPB][8];

    // ---- Phase 1: thread = hidden unit j = tid, 4 walkers at once ----
    // z values are BLOCK-UNIFORM: index x with wave-uniform addresses so the
    // compiler emits s_load into SGPRs; each FMA reads its z as the one free
    // SGPR operand. No readlanes, no LDS, no barrier before phase 1.
    const float* __restrict__ xb = x + w0 * NIN;

    float a0 = b1[tid];
    float a1 = a0, a2 = a0, a3 = a0;
    float csum = 0.f;
    #pragma unroll
    for (int i = 0; i < NIN; ++i) {
        const float wv = W1[i * HID + tid];
        a0 = fmaf(xb[0 * NIN + i], wv, a0);
        a1 = fmaf(xb[1 * NIN + i], wv, a1);
        a2 = fmaf(xb[2 * NIN + i], wv, a2);
        a3 = fmaf(xb[3 * NIN + i], wv, a3);
        csum = fmaf(wv, wv, csum);
    }
    const float w2 = W2[tid];
    const int hi = tid >> 7, lo = tid & 127;

    #pragma unroll
    for (int w = 0; w < WPB; ++w) {
        const float a = (w == 0) ? a0 : (w == 1) ? a1 : (w == 2) ? a2 : a3;
        // fast tanh: t = 1 - 2/(exp(2a)+1)
        const float e = __expf(2.f * a);
        const float t = 1.f - 2.f * __builtin_amdgcn_rcpf(e + 1.f);
        const float s = 1.f - t * t;
        us[w][hi][lo]   = w2 * s;                    // gradient coefficient u_j
        ls[tid * 5 + w] = -2.f * w2 * t * s * csum;  // laplacian term of unit j
    }
    __syncthreads();

    // ---- Phase 2 ----
    if (tid < 192) {
        // gradient g_i: (w = tid&3, c = (tid>>2)&1, r = tid>>3), 128-elem dot
        const int w = tid & 3, c = (tid >> 2) & 1, r = tid >> 3;
        const float4* gp = (const float4*)(W1 + r * HID + c * 128);
        const float4* up = (const float4*)&us[w][c][0];
        float g = 0.f;
        #pragma unroll 4
        for (int k = 0; k < 32; ++k) {
            const float4 wv = gp[k];
            const float4 uv = up[k];
            g = fmaf(wv.x, uv.x, g);
            g = fmaf(wv.y, uv.y, g);
            g = fmaf(wv.z, uv.z, g);
            g = fmaf(wv.w, uv.w, g);
        }
        g += __shfl_xor(g, 4, 64);    // combine the two 128-chunks (bit2 = c)
        if (c == 0) gs[w][r] = g * g;
    } else if (tid < 224) {
        // laplacian: 32 lanes of wave 3 comb-reduce ls (conflict-free pattern)
        const int p = tid - 192, w = p >> 3, k = p & 7;
        float sacc = 0.f;
        #pragma unroll
        for (int t = 0; t < 32; ++t) sacc += ls[(8 * t + k) * 5 + w];
        lp[w][k] = sacc;
    }
    __syncthreads();

    if (tid < WPB) {
        float gg = 0.f;
        #pragma unroll
        for (int r = 0; r < 24; ++r) gg += gs[tid][r];
        float lap = 0.f;
        #pragma unroll
        for (int k = 0; k < 8; ++k) lap += lp[tid][k];
        out[w0 + tid] = -0.5f * (lap + gg);
    }
}

extern "C" void kernel_launch(void* const* d_in, const int* in_sizes, int n_in,
                              void* d_out, int out_size, void* d_ws, size_t ws_size,
                              hipStream_t stream) {
    const float* x  = (const float*)d_in[0];  // [4096, 8, 3]
    const float* W1 = (const float*)d_in[1];  // [24, 256]
    const float* b1 = (const float*)d_in[2];  // [256]
    const float* W2 = (const float*)d_in[3];  // [256, 1]
    // d_in[4] = b2 unused (constant offset drops out of derivatives)
    float* out = (float*)d_out;               // [4096]

    kinetic_kernel<<<NWALKERS / WPB, HID, 0, stream>>>(x, W1, b1, W2, out);
}